// Round 6
// baseline (395.285 us; speedup 1.0000x reference)
//
#include <hip/hip_runtime.h>
#include <hip/hip_bf16.h>
#include <stdint.h>

#define NN 100000
#define NE 1600000
#define NB 98                   // ceil(NN/1024) scan blocks
#define CP 16                   // cnt padding: one counter per 64-B line

// ---------------- edge_index width detection (int32 vs int64) ----------------

__global__ void k_detect(const int* __restrict__ ei, int* __restrict__ flag) {
    if (threadIdx.x == 0) {
        int z = 0;
#pragma unroll
        for (int i = 0; i < 16; ++i) z |= ei[2 * i + 1];
        flag[0] = (z == 0) ? 1 : 0;
    }
}

// ---------------- CSR build ----------------
// k_count: 8 edges/thread; histogram into LINE-PADDED counters (cnt[d*16])
// to kill cross-XCD false sharing; rank = atomic return, coalesced store.

__global__ void k_count(const int* __restrict__ ei, const int* __restrict__ flag,
                        int* __restrict__ cnt, int* __restrict__ rank) {
    int base = (blockIdx.x * 256 + threadIdx.x) * 8;
    if (base >= NE) return;                      // NE % 8 == 0
    int is64 = flag[0];
    int d[8];
    if (is64) {
        const int4* p = (const int4*)ei;
        int idx = (NE + base) >> 1;
#pragma unroll
        for (int j = 0; j < 4; ++j) {
            int4 v = p[idx + j];
            d[2 * j] = v.x; d[2 * j + 1] = v.z;
        }
    } else {
        int4 a = *(const int4*)&ei[NE + base];
        int4 b = *(const int4*)&ei[NE + base + 4];
        d[0] = a.x; d[1] = a.y; d[2] = a.z; d[3] = a.w;
        d[4] = b.x; d[5] = b.y; d[6] = b.z; d[7] = b.w;
    }
    int r[8];
#pragma unroll
    for (int j = 0; j < 8; ++j) r[j] = atomicAdd(&cnt[d[j] * CP], 1);
    *(int4*)&rank[base] = make_int4(r[0], r[1], r[2], r[3]);
    *(int4*)&rank[base + 4] = make_int4(r[4], r[5], r[6], r[7]);
}

// block-level partial sums for the scan + dinv computation (fused)
__global__ void k_scan1(const int* __restrict__ cnt, int* __restrict__ bsum,
                        float* __restrict__ dinv) {
    __shared__ int sh[256];
    int t = threadIdx.x;
    int base = blockIdx.x * 1024 + t * 4;
    int s = 0;
#pragma unroll
    for (int j = 0; j < 4; ++j) {
        int i = base + j;
        if (i < NN) {
            int c = cnt[i * CP];
            s += c;
            dinv[i] = rsqrtf((float)c + 1.0f);
        }
    }
    sh[t] = s; __syncthreads();
    for (int off = 128; off > 0; off >>= 1) {
        if (t < off) sh[t] += sh[t + off];
        __syncthreads();
    }
    if (t == 0) bsum[blockIdx.x] = sh[0];
}

// one-wave exclusive scan over NB<=128 block sums
__global__ void k_scan2(const int* __restrict__ bsum, int* __restrict__ boff,
                        int* __restrict__ rs) {
    int l = threadIdx.x;                 // 64 threads
    int a = (l < NB) ? bsum[l] : 0;
    int b = (64 + l < NB) ? bsum[64 + l] : 0;
    int ia = a, ib = b;
    for (int off = 1; off < 64; off <<= 1) {
        int t = __shfl_up(ia, off);
        if (l >= off) ia += t;
        t = __shfl_up(ib, off);
        if (l >= off) ib += t;
    }
    int tot_a = __shfl(ia, 63);
    if (l < NB) boff[l] = ia - a;
    if (64 + l < NB) boff[64 + l] = tot_a + ib - b;
    if (l == 0) rs[NN] = NE;
}

__global__ void k_scan3(const int* __restrict__ cnt, const int* __restrict__ boff,
                        int* __restrict__ rs) {
    __shared__ int sh[256];
    int t = threadIdx.x;
    int base = blockIdx.x * 1024 + t * 4;
    int v[4]; int s = 0;
#pragma unroll
    for (int j = 0; j < 4; ++j) {
        int i = base + j;
        v[j] = (i < NN) ? cnt[i * CP] : 0;
        s += v[j];
    }
    sh[t] = s; __syncthreads();
    for (int off = 1; off < 256; off <<= 1) {
        int tmp = (t >= off) ? sh[t - off] : 0;
        __syncthreads();
        sh[t] += tmp;
        __syncthreads();
    }
    int run = sh[t] - s + boff[blockIdx.x];
#pragma unroll
    for (int j = 0; j < 4; ++j) {
        int i = base + j;
        if (i < NN) { rs[i] = run; run += v[j]; }
    }
}

// csr entry: (src*16) in bits 0..20 (float4-row base), src in-degree (cap 2047)
// in bits 21..31. Atomic-free: pos = rs[d] + rank[e]. 4 edges/thread for ILP.
__global__ void k_fill(const int* __restrict__ ei, const int* __restrict__ flag,
                       const int* __restrict__ cnt, const int* __restrict__ rs,
                       const int* __restrict__ rank, unsigned* __restrict__ csr) {
    int base = (blockIdx.x * 256 + threadIdx.x) * 4;
    if (base >= NE) return;                      // NE % 4 == 0
    int is64 = flag[0];
    int s[4], d[4];
    if (is64) {
        const int4* p = (const int4*)ei;
#pragma unroll
        for (int j = 0; j < 2; ++j) {
            int4 v = p[(base >> 1) + j];
            s[2 * j] = v.x; s[2 * j + 1] = v.z;
            int4 w = p[((NE + base) >> 1) + j];
            d[2 * j] = w.x; d[2 * j + 1] = w.z;
        }
    } else {
        int4 sv = *(const int4*)&ei[base];
        int4 dv = *(const int4*)&ei[NE + base];
        s[0] = sv.x; s[1] = sv.y; s[2] = sv.z; s[3] = sv.w;
        d[0] = dv.x; d[1] = dv.y; d[2] = dv.z; d[3] = dv.w;
    }
    int4 rk = *(const int4*)&rank[base];
    int rka[4] = {rk.x, rk.y, rk.z, rk.w};
#pragma unroll
    for (int j = 0; j < 4; ++j) {
        int pos = rs[d[j]] + rka[j];
        unsigned deg = (unsigned)min(cnt[s[j] * CP], 2047);
        csr[pos] = ((unsigned)s[j] << 4) | (deg << 21);
    }
}

// ---------------- fp32 GEMM: H[N,64] = X[N,64] @ W[64,64] ----------------
// lane = row: lane-distinct X loads (1 KB/instr); W reads wave-uniform.

__global__ void __launch_bounds__(256) k_gemm(const float* __restrict__ X,
                                              const float* __restrict__ W,
                                              float* __restrict__ H) {
    int wid = (blockIdx.x * blockDim.x + threadIdx.x) >> 6;
    int nw = (gridDim.x * blockDim.x) >> 6;
    int lane = threadIdx.x & 63;
    const int ntiles = (NN + 63) >> 6;          // 1563 (last tile ragged)
    for (int t = wid; t < ntiles; t += nw) {
        int row = t * 64 + lane;
        int r = row < NN ? row : NN - 1;        // clamped lanes write duplicate data
        const float4* xp = (const float4*)(X + (size_t)r * 64);
        float acc[64];
#pragma unroll
        for (int c = 0; c < 64; ++c) acc[c] = 0.f;
#pragma unroll 4
        for (int k4 = 0; k4 < 16; ++k4) {
            float4 xv = xp[k4];
#pragma unroll
            for (int kj = 0; kj < 4; ++kj) {
                float xk = (kj == 0) ? xv.x : (kj == 1) ? xv.y : (kj == 2) ? xv.z : xv.w;
                const float4* wr = (const float4*)(W + (k4 * 4 + kj) * 64);
#pragma unroll
                for (int c4 = 0; c4 < 16; ++c4) {
                    float4 wv = wr[c4];
                    acc[c4 * 4 + 0] += xk * wv.x;
                    acc[c4 * 4 + 1] += xk * wv.y;
                    acc[c4 * 4 + 2] += xk * wv.z;
                    acc[c4 * 4 + 3] += xk * wv.w;
                }
            }
        }
        float4* op = (float4*)(H + (size_t)r * 64);
#pragma unroll
        for (int c4 = 0; c4 < 16; ++c4)
            op[c4] = make_float4(acc[c4 * 4], acc[c4 * 4 + 1],
                                 acc[c4 * 4 + 2], acc[c4 * 4 + 3]);
    }
}

// ---------------- aggregation: one wave per node, 16 lanes x float4 per row,
// 4 lane-groups x 4-deep unroll => 16 row-gathers in flight per wave ----------

__global__ void __launch_bounds__(256) k_agg(const float4* __restrict__ h4,
                                             const int* __restrict__ rs,
                                             const unsigned* __restrict__ csr,
                                             const float* __restrict__ dinv,
                                             const float* __restrict__ bias,
                                             float4* __restrict__ out4) {
    int wid = (blockIdx.x * blockDim.x + threadIdx.x) >> 6;
    int lane = threadIdx.x & 63;
    int node = __builtin_amdgcn_readfirstlane(wid);
    if (node >= NN) return;
    int g = lane >> 4;        // edge-slot group 0..3
    int fl = lane & 15;       // feature quad 0..15
    float dn = dinv[node];
    int e0 = rs[node], e1 = rs[node + 1];
    float4 hrow = h4[node * 16 + fl];          // self row
    float ax = 0.f, ay = 0.f, az = 0.f, aw = 0.f;
    int e = e0 + g;
    for (; e + 12 < e1; e += 16) {             // 4 edges per group in flight
        unsigned p0 = csr[e];
        unsigned p1 = csr[e + 4];
        unsigned p2 = csr[e + 8];
        unsigned p3 = csr[e + 12];
        float4 r0 = h4[(p0 & 0x1FFFFFu) + fl];
        float4 r1 = h4[(p1 & 0x1FFFFFu) + fl];
        float4 r2 = h4[(p2 & 0x1FFFFFu) + fl];
        float4 r3 = h4[(p3 & 0x1FFFFFu) + fl];
        float w0 = rsqrtf((float)(p0 >> 21) + 1.0f);
        float w1 = rsqrtf((float)(p1 >> 21) + 1.0f);
        float w2 = rsqrtf((float)(p2 >> 21) + 1.0f);
        float w3 = rsqrtf((float)(p3 >> 21) + 1.0f);
        ax += r0.x * w0; ay += r0.y * w0; az += r0.z * w0; aw += r0.w * w0;
        ax += r1.x * w1; ay += r1.y * w1; az += r1.z * w1; aw += r1.w * w1;
        ax += r2.x * w2; ay += r2.y * w2; az += r2.z * w2; aw += r2.w * w2;
        ax += r3.x * w3; ay += r3.y * w3; az += r3.z * w3; aw += r3.w * w3;
    }
    for (; e < e1; e += 4) {
        unsigned p0 = csr[e];
        float4 r0 = h4[(p0 & 0x1FFFFFu) + fl];
        float w0 = rsqrtf((float)(p0 >> 21) + 1.0f);
        ax += r0.x * w0; ay += r0.y * w0; az += r0.z * w0; aw += r0.w * w0;
    }
    ax += __shfl_xor(ax, 16); ay += __shfl_xor(ay, 16);
    az += __shfl_xor(az, 16); aw += __shfl_xor(aw, 16);
    ax += __shfl_xor(ax, 32); ay += __shfl_xor(ay, 32);
    az += __shfl_xor(az, 32); aw += __shfl_xor(aw, 32);
    if (lane < 16) {
        const float4 b4 = *(const float4*)&bias[fl * 4];
        float4 res;
        res.x = fmaxf((ax + hrow.x * dn) * dn + b4.x, 0.f);
        res.y = fmaxf((ay + hrow.y * dn) * dn + b4.y, 0.f);
        res.z = fmaxf((az + hrow.z * dn) * dn + b4.z, 0.f);
        res.w = fmaxf((aw + hrow.w * dn) * dn + b4.w, 0.f);
        out4[node * 16 + fl] = res;
    }
}

// ---------------- launch ----------------

extern "C" void kernel_launch(void* const* d_in, const int* in_sizes, int n_in,
                              void* d_out, int out_size, void* d_ws, size_t ws_size,
                              hipStream_t stream) {
    const float* x  = (const float*)d_in[0];            // [NN,64] fp32
    const int* ei   = (const int*)d_in[1];              // [2,NE] int32/int64 (detected)
    const float* W1 = (const float*)d_in[2];
    const float* b1 = (const float*)d_in[3];
    const float* W2 = (const float*)d_in[4];
    const float* b2 = (const float*)d_in[5];

    char* ws = (char*)d_ws;
    size_t off = 0;
    auto alloc = [&](size_t bytes) -> char* {
        char* p = ws + off;
        off = (off + bytes + 511) & ~(size_t)511;
        return p;
    };
    int*      cnt  = (int*)alloc((size_t)NN * CP * 4);  // 6.4 MB line-padded
    float*    dinv = (float*)alloc((size_t)NN * 4);
    int*      rs   = (int*)alloc((size_t)(NN + 1) * 4);
    int*      bsum = (int*)alloc((size_t)NB * 4);
    int*      boff = (int*)alloc((size_t)NB * 4);
    int*      flag = (int*)alloc(64);
    int*      rank = (int*)alloc((size_t)NE * 4);       // 6.4 MB
    unsigned* csr  = (unsigned*)alloc((size_t)NE * 4);  // 6.4 MB
    float*    hA   = (float*)alloc((size_t)NN * 64 * 4);
    float*    hB   = (float*)d_out;                     // reuse d_out as layer-1 act

    hipMemsetAsync(cnt, 0, (size_t)NN * CP * 4, stream);
    k_detect<<<1, 64, 0, stream>>>(ei, flag);
    k_count<<<(NE / 8 + 255) / 256, 256, 0, stream>>>(ei, flag, cnt, rank);
    k_scan1<<<NB, 256, 0, stream>>>(cnt, bsum, dinv);
    k_scan2<<<1, 64, 0, stream>>>(bsum, boff, rs);
    k_scan3<<<NB, 256, 0, stream>>>(cnt, boff, rs);
    k_fill<<<(NE / 4 + 255) / 256, 256, 0, stream>>>(ei, flag, cnt, rs, rank, csr);

    // layer 1
    k_gemm<<<391, 256, 0, stream>>>(x, W1, hA);
    k_agg<<<(NN * 64) / 256, 256, 0, stream>>>((const float4*)hA, rs, csr, dinv, b1,
                                               (float4*)hB);
    // layer 2
    k_gemm<<<391, 256, 0, stream>>>(hB, W2, hA);
    k_agg<<<(NN * 64) / 256, 256, 0, stream>>>((const float4*)hA, rs, csr, dinv, b2,
                                               (float4*)d_out);
}

// Round 7
// 332.405 us; speedup vs baseline: 1.1892x; 1.1892x over previous
//
#include <hip/hip_runtime.h>
#include <hip/hip_bf16.h>
#include <stdint.h>

#define NN 100000
#define NE 1600000
#define NBLK 256                 // edge-chunk blocks for hist/scatter
#define EPB (NE / NBLK)          // 6250 edges per block
#define NBINS 782                // ceil(NN/128) coarse bins of 128 nodes
#define NCELL (NBINS * NBLK)     // 200192 scan cells
#define NSB ((NCELL + 1023) / 1024)  // 196 scan blocks

// ---------------- edge_index width detection (int32 vs int64) ----------------

__global__ void k_detect(const int* __restrict__ ei, int* __restrict__ flag) {
    if (threadIdx.x == 0) {
        int z = 0;
#pragma unroll
        for (int i = 0; i < 16; ++i) z |= ei[2 * i + 1];
        flag[0] = (z == 0) ? 1 : 0;
    }
}

// ---------------- CSR build via 2-level counting sort (NO global atomics) ----

// Phase A: per-block LDS histogram over coarse bins (dst>>7).
__global__ void __launch_bounds__(256) k_hist(const int* __restrict__ ei,
                                              const int* __restrict__ flag,
                                              int* __restrict__ gcount) {
    __shared__ int lbin[NBINS];
    int t = threadIdx.x, blk = blockIdx.x;
    for (int i = t; i < NBINS; i += 256) lbin[i] = 0;
    __syncthreads();
    int is64 = flag[0];
    int e0 = blk * EPB;
    if (is64) {
        const int2* p = (const int2*)ei;
        for (int e = e0 + t; e < e0 + EPB; e += 256)
            atomicAdd(&lbin[p[NE + e].x >> 7], 1);
    } else {
        for (int e = e0 + t; e < e0 + EPB; e += 256)
            atomicAdd(&lbin[ei[NE + e] >> 7], 1);
    }
    __syncthreads();
    for (int b = t; b < NBINS; b += 256) gcount[b * NBLK + blk] = lbin[b];
}

// Phase B: exclusive scan over NCELL cells (bin-major).
__global__ void k_pscan1(const int* __restrict__ g, int* __restrict__ bsum) {
    __shared__ int sh[256];
    int t = threadIdx.x;
    int base = blockIdx.x * 1024 + t * 4;
    int s = 0;
#pragma unroll
    for (int j = 0; j < 4; ++j) { int i = base + j; if (i < NCELL) s += g[i]; }
    sh[t] = s; __syncthreads();
    for (int off = 128; off > 0; off >>= 1) {
        if (t < off) sh[t] += sh[t + off];
        __syncthreads();
    }
    if (t == 0) bsum[blockIdx.x] = sh[0];
}

__global__ void k_pscan2(const int* __restrict__ bsum, int* __restrict__ boff) {
    __shared__ int sh[256];
    int t = threadIdx.x;
    int v = (t < NSB) ? bsum[t] : 0;
    sh[t] = v; __syncthreads();
    for (int off = 1; off < 256; off <<= 1) {
        int tmp = (t >= off) ? sh[t - off] : 0;
        __syncthreads();
        sh[t] += tmp;
        __syncthreads();
    }
    if (t < NSB) boff[t] = sh[t] - v;
}

__global__ void k_pscan3(const int* __restrict__ g, const int* __restrict__ boff,
                         int* __restrict__ goff) {
    __shared__ int sh[256];
    int t = threadIdx.x;
    int base = blockIdx.x * 1024 + t * 4;
    int v[4]; int s = 0;
#pragma unroll
    for (int j = 0; j < 4; ++j) { int i = base + j; v[j] = (i < NCELL) ? g[i] : 0; s += v[j]; }
    sh[t] = s; __syncthreads();
    for (int off = 1; off < 256; off <<= 1) {
        int tmp = (t >= off) ? sh[t - off] : 0;
        __syncthreads();
        sh[t] += tmp;
        __syncthreads();
    }
    int run = sh[t] - s + boff[blockIdx.x];
#pragma unroll
    for (int j = 0; j < 4; ++j) {
        int i = base + j;
        if (i < NCELL) { goff[i] = run; run += v[j]; }
    }
}

// Phase C: scatter edges into coarse-bin-grouped tmp. LDS-atomic local rank.
// tmp entry: src (17 bits) | d_low7 << 17.
__global__ void __launch_bounds__(256) k_scatter(const int* __restrict__ ei,
                                                 const int* __restrict__ flag,
                                                 const int* __restrict__ goff,
                                                 unsigned* __restrict__ tmp) {
    __shared__ int lcur[NBINS];
    int t = threadIdx.x, blk = blockIdx.x;
    for (int i = t; i < NBINS; i += 256) lcur[i] = 0;
    __syncthreads();
    int is64 = flag[0];
    int e0 = blk * EPB;
    for (int e = e0 + t; e < e0 + EPB; e += 256) {
        int s, d;
        if (is64) {
            s = ((const int2*)ei)[e].x;
            d = ((const int2*)ei)[NE + e].x;
        } else {
            s = ei[e];
            d = ei[NE + e];
        }
        int b = d >> 7;
        int lr = atomicAdd(&lcur[b], 1);
        int pos = goff[b * NBLK + blk] + lr;
        tmp[pos] = (unsigned)s | ((unsigned)(d & 127) << 17);
    }
}

// Phase D1: per-bin node histogram -> rs, deg, dinv.
__global__ void __launch_bounds__(256) k_deg(const unsigned* __restrict__ tmp,
                                             const int* __restrict__ goff,
                                             int* __restrict__ rs,
                                             int* __restrict__ deg32,
                                             float* __restrict__ dinv) {
    __shared__ int hist[128];
    int b = blockIdx.x, t = threadIdx.x;
    if (t < 128) hist[t] = 0;
    __syncthreads();
    int bs = goff[b * NBLK];
    int be = (b == NBINS - 1) ? NE : goff[(b + 1) * NBLK];
    for (int e = bs + t; e < be; e += 256)
        atomicAdd(&hist[tmp[e] >> 17], 1);
    __syncthreads();
    if (t < 128) {
        int node = b * 128 + t;
        if (node < NN) {
            int c = hist[t];
            int loff = 0;
            for (int i = 0; i < t; ++i) loff += hist[i];
            rs[node] = bs + loff;
            deg32[node] = c;
            dinv[node] = rsqrtf((float)c + 1.0f);
        }
    }
    if (b == 0 && t == 0) rs[NN] = NE;
}

// Phase D2: per-bin scatter into final csr. Entry: (src*16) | (deg<<21),
// identical format to what k_agg consumes.
__global__ void __launch_bounds__(256) k_csr(const unsigned* __restrict__ tmp,
                                             const int* __restrict__ goff,
                                             const int* __restrict__ rs,
                                             const int* __restrict__ deg32,
                                             unsigned* __restrict__ csr) {
    __shared__ int cur[128];
    __shared__ int base_sh[128];
    int b = blockIdx.x, t = threadIdx.x;
    if (t < 128) {
        cur[t] = 0;
        int node = b * 128 + t;
        base_sh[t] = (node < NN) ? rs[node] : 0;
    }
    __syncthreads();
    int bs = goff[b * NBLK];
    int be = (b == NBINS - 1) ? NE : goff[(b + 1) * NBLK];
    for (int e = bs + t; e < be; e += 256) {
        unsigned v = tmp[e];
        int dl = v >> 17;
        unsigned s = v & 0x1FFFFu;
        int lr = atomicAdd(&cur[dl], 1);
        unsigned deg = (unsigned)min(deg32[s], 2047);
        csr[base_sh[dl] + lr] = (s << 4) | (deg << 21);
    }
}

// ---------------- fp32 GEMM: H[N,64] = X[N,64] @ W[64,64] ----------------
// lane = row: lane-distinct X loads (1 KB/instr); W reads wave-uniform.

__global__ void __launch_bounds__(256) k_gemm(const float* __restrict__ X,
                                              const float* __restrict__ W,
                                              float* __restrict__ H) {
    int wid = (blockIdx.x * blockDim.x + threadIdx.x) >> 6;
    int nw = (gridDim.x * blockDim.x) >> 6;
    int lane = threadIdx.x & 63;
    const int ntiles = (NN + 63) >> 6;          // 1563 (last tile ragged)
    for (int t = wid; t < ntiles; t += nw) {
        int row = t * 64 + lane;
        int r = row < NN ? row : NN - 1;        // clamped lanes write duplicate data
        const float4* xp = (const float4*)(X + (size_t)r * 64);
        float acc[64];
#pragma unroll
        for (int c = 0; c < 64; ++c) acc[c] = 0.f;
#pragma unroll 4
        for (int k4 = 0; k4 < 16; ++k4) {
            float4 xv = xp[k4];
#pragma unroll
            for (int kj = 0; kj < 4; ++kj) {
                float xk = (kj == 0) ? xv.x : (kj == 1) ? xv.y : (kj == 2) ? xv.z : xv.w;
                const float4* wr = (const float4*)(W + (k4 * 4 + kj) * 64);
#pragma unroll
                for (int c4 = 0; c4 < 16; ++c4) {
                    float4 wv = wr[c4];
                    acc[c4 * 4 + 0] += xk * wv.x;
                    acc[c4 * 4 + 1] += xk * wv.y;
                    acc[c4 * 4 + 2] += xk * wv.z;
                    acc[c4 * 4 + 3] += xk * wv.w;
                }
            }
        }
        float4* op = (float4*)(H + (size_t)r * 64);
#pragma unroll
        for (int c4 = 0; c4 < 16; ++c4)
            op[c4] = make_float4(acc[c4 * 4], acc[c4 * 4 + 1],
                                 acc[c4 * 4 + 2], acc[c4 * 4 + 3]);
    }
}

// ---------------- aggregation: one wave per node, 16 lanes x float4 per row,
// 4 lane-groups x 4-deep unroll => 16 row-gathers in flight per wave ----------

__global__ void __launch_bounds__(256) k_agg(const float4* __restrict__ h4,
                                             const int* __restrict__ rs,
                                             const unsigned* __restrict__ csr,
                                             const float* __restrict__ dinv,
                                             const float* __restrict__ bias,
                                             float4* __restrict__ out4) {
    int wid = (blockIdx.x * blockDim.x + threadIdx.x) >> 6;
    int lane = threadIdx.x & 63;
    int node = __builtin_amdgcn_readfirstlane(wid);
    if (node >= NN) return;
    int g = lane >> 4;        // edge-slot group 0..3
    int fl = lane & 15;       // feature quad 0..15
    float dn = dinv[node];
    int e0 = rs[node], e1 = rs[node + 1];
    float4 hrow = h4[node * 16 + fl];          // self row
    float ax = 0.f, ay = 0.f, az = 0.f, aw = 0.f;
    int e = e0 + g;
    for (; e + 12 < e1; e += 16) {             // 4 edges per group in flight
        unsigned p0 = csr[e];
        unsigned p1 = csr[e + 4];
        unsigned p2 = csr[e + 8];
        unsigned p3 = csr[e + 12];
        float4 r0 = h4[(p0 & 0x1FFFFFu) + fl];
        float4 r1 = h4[(p1 & 0x1FFFFFu) + fl];
        float4 r2 = h4[(p2 & 0x1FFFFFu) + fl];
        float4 r3 = h4[(p3 & 0x1FFFFFu) + fl];
        float w0 = rsqrtf((float)(p0 >> 21) + 1.0f);
        float w1 = rsqrtf((float)(p1 >> 21) + 1.0f);
        float w2 = rsqrtf((float)(p2 >> 21) + 1.0f);
        float w3 = rsqrtf((float)(p3 >> 21) + 1.0f);
        ax += r0.x * w0; ay += r0.y * w0; az += r0.z * w0; aw += r0.w * w0;
        ax += r1.x * w1; ay += r1.y * w1; az += r1.z * w1; aw += r1.w * w1;
        ax += r2.x * w2; ay += r2.y * w2; az += r2.z * w2; aw += r2.w * w2;
        ax += r3.x * w3; ay += r3.y * w3; az += r3.z * w3; aw += r3.w * w3;
    }
    for (; e < e1; e += 4) {
        unsigned p0 = csr[e];
        float4 r0 = h4[(p0 & 0x1FFFFFu) + fl];
        float w0 = rsqrtf((float)(p0 >> 21) + 1.0f);
        ax += r0.x * w0; ay += r0.y * w0; az += r0.z * w0; aw += r0.w * w0;
    }
    ax += __shfl_xor(ax, 16); ay += __shfl_xor(ay, 16);
    az += __shfl_xor(az, 16); aw += __shfl_xor(aw, 16);
    ax += __shfl_xor(ax, 32); ay += __shfl_xor(ay, 32);
    az += __shfl_xor(az, 32); aw += __shfl_xor(aw, 32);
    if (lane < 16) {
        const float4 b4 = *(const float4*)&bias[fl * 4];
        float4 res;
        res.x = fmaxf((ax + hrow.x * dn) * dn + b4.x, 0.f);
        res.y = fmaxf((ay + hrow.y * dn) * dn + b4.y, 0.f);
        res.z = fmaxf((az + hrow.z * dn) * dn + b4.z, 0.f);
        res.w = fmaxf((aw + hrow.w * dn) * dn + b4.w, 0.f);
        out4[node * 16 + fl] = res;
    }
}

// ---------------- launch ----------------

extern "C" void kernel_launch(void* const* d_in, const int* in_sizes, int n_in,
                              void* d_out, int out_size, void* d_ws, size_t ws_size,
                              hipStream_t stream) {
    const float* x  = (const float*)d_in[0];            // [NN,64] fp32
    const int* ei   = (const int*)d_in[1];              // [2,NE] int32/int64 (detected)
    const float* W1 = (const float*)d_in[2];
    const float* b1 = (const float*)d_in[3];
    const float* W2 = (const float*)d_in[4];
    const float* b2 = (const float*)d_in[5];

    char* ws = (char*)d_ws;
    size_t off = 0;
    auto alloc = [&](size_t bytes) -> char* {
        char* p = ws + off;
        off = (off + bytes + 511) & ~(size_t)511;
        return p;
    };
    int*      flag  = (int*)alloc(64);
    int*      gcount= (int*)alloc((size_t)NCELL * 4);    // 800 KB
    int*      goff  = (int*)alloc((size_t)NCELL * 4);    // 800 KB
    int*      bsum  = (int*)alloc((size_t)NSB * 4);
    int*      boff  = (int*)alloc((size_t)NSB * 4);
    unsigned* tmp   = (unsigned*)alloc((size_t)NE * 4);  // 6.4 MB
    unsigned* csr   = (unsigned*)alloc((size_t)NE * 4);  // 6.4 MB
    int*      rs    = (int*)alloc((size_t)(NN + 1) * 4);
    int*      deg32 = (int*)alloc((size_t)NN * 4);
    float*    dinv  = (float*)alloc((size_t)NN * 4);
    float*    hA    = (float*)alloc((size_t)NN * 64 * 4);
    float*    hB    = (float*)d_out;                     // reuse d_out as layer-1 act

    k_detect<<<1, 64, 0, stream>>>(ei, flag);
    k_hist<<<NBLK, 256, 0, stream>>>(ei, flag, gcount);
    k_pscan1<<<NSB, 256, 0, stream>>>(gcount, bsum);
    k_pscan2<<<1, 256, 0, stream>>>(bsum, boff);
    k_pscan3<<<NSB, 256, 0, stream>>>(gcount, boff, goff);
    k_scatter<<<NBLK, 256, 0, stream>>>(ei, flag, goff, tmp);
    k_deg<<<NBINS, 256, 0, stream>>>(tmp, goff, rs, deg32, dinv);
    k_csr<<<NBINS, 256, 0, stream>>>(tmp, goff, rs, deg32, csr);

    // layer 1
    k_gemm<<<391, 256, 0, stream>>>(x, W1, hA);
    k_agg<<<(NN * 64) / 256, 256, 0, stream>>>((const float4*)hA, rs, csr, dinv, b1,
                                               (float4*)hB);
    // layer 2
    k_gemm<<<391, 256, 0, stream>>>(hB, W2, hA);
    k_agg<<<(NN * 64) / 256, 256, 0, stream>>>((const float4*)hA, rs, csr, dinv, b2,
                                               (float4*)d_out);
}

// Round 9
// 321.312 us; speedup vs baseline: 1.2302x; 1.0345x over previous
//
#include <hip/hip_runtime.h>
#include <hip/hip_bf16.h>
#include <stdint.h>

#define NN 100000
#define NE 1600000
#define NBLK 256                 // edge-chunk blocks for hist/scatter
#define EPB (NE / NBLK)          // 6250 edges per block
#define NBINS 782                // ceil(NN/128) coarse bins of 128 nodes
#define NCELL (NBINS * NBLK)     // 200192 scan cells
#define NSB ((NCELL + 1023) / 1024)  // 196 scan blocks

// ---------------- bf16 helpers ----------------

__device__ __forceinline__ unsigned pack_bf16(float a, float b) {
    unsigned ua = __float_as_uint(a);
    unsigned ub = __float_as_uint(b);
    ua += 0x7FFFu + ((ua >> 16) & 1u);       // RNE
    ub += 0x7FFFu + ((ub >> 16) & 1u);
    return (ua >> 16) | (ub & 0xFFFF0000u);  // a -> low half (element 2k)
}
#define BF_LO(w) __uint_as_float((w) << 16)
#define BF_HI(w) __uint_as_float((w) & 0xFFFF0000u)

// ---------------- edge_index width detection (int32 vs int64) ----------------

__global__ void k_detect(const int* __restrict__ ei, int* __restrict__ flag) {
    if (threadIdx.x == 0) {
        int z = 0;
#pragma unroll
        for (int i = 0; i < 16; ++i) z |= ei[2 * i + 1];
        flag[0] = (z == 0) ? 1 : 0;
    }
}

// ---------------- CSR build via 2-level counting sort (NO global atomics) ----

__global__ void __launch_bounds__(256) k_hist(const int* __restrict__ ei,
                                              const int* __restrict__ flag,
                                              int* __restrict__ gcount) {
    __shared__ int lbin[NBINS];
    int t = threadIdx.x, blk = blockIdx.x;
    for (int i = t; i < NBINS; i += 256) lbin[i] = 0;
    __syncthreads();
    int is64 = flag[0];
    int e0 = blk * EPB;
    if (is64) {
        const int2* p = (const int2*)ei;
        for (int e = e0 + t; e < e0 + EPB; e += 256)
            atomicAdd(&lbin[p[NE + e].x >> 7], 1);
    } else {
        for (int e = e0 + t; e < e0 + EPB; e += 256)
            atomicAdd(&lbin[ei[NE + e] >> 7], 1);
    }
    __syncthreads();
    for (int b = t; b < NBINS; b += 256) gcount[b * NBLK + blk] = lbin[b];
}

__global__ void k_pscan1(const int* __restrict__ g, int* __restrict__ bsum) {
    __shared__ int sh[256];
    int t = threadIdx.x;
    int base = blockIdx.x * 1024 + t * 4;
    int s = 0;
#pragma unroll
    for (int j = 0; j < 4; ++j) { int i = base + j; if (i < NCELL) s += g[i]; }
    sh[t] = s; __syncthreads();
    for (int off = 128; off > 0; off >>= 1) {
        if (t < off) sh[t] += sh[t + off];
        __syncthreads();
    }
    if (t == 0) bsum[blockIdx.x] = sh[0];
}

__global__ void k_pscan2(const int* __restrict__ bsum, int* __restrict__ boff) {
    __shared__ int sh[256];
    int t = threadIdx.x;
    int v = (t < NSB) ? bsum[t] : 0;
    sh[t] = v; __syncthreads();
    for (int off = 1; off < 256; off <<= 1) {
        int tmp = (t >= off) ? sh[t - off] : 0;
        __syncthreads();
        sh[t] += tmp;
        __syncthreads();
    }
    if (t < NSB) boff[t] = sh[t] - v;
}

__global__ void k_pscan3(const int* __restrict__ g, const int* __restrict__ boff,
                         int* __restrict__ goff) {
    __shared__ int sh[256];
    int t = threadIdx.x;
    int base = blockIdx.x * 1024 + t * 4;
    int v[4]; int s = 0;
#pragma unroll
    for (int j = 0; j < 4; ++j) { int i = base + j; v[j] = (i < NCELL) ? g[i] : 0; s += v[j]; }
    sh[t] = s; __syncthreads();
    for (int off = 1; off < 256; off <<= 1) {
        int tmp = (t >= off) ? sh[t - off] : 0;
        __syncthreads();
        sh[t] += tmp;
        __syncthreads();
    }
    int run = sh[t] - s + boff[blockIdx.x];
#pragma unroll
    for (int j = 0; j < 4; ++j) {
        int i = base + j;
        if (i < NCELL) { goff[i] = run; run += v[j]; }
    }
}

// tmp entry: src (17 bits) | d_low7 << 17.
__global__ void __launch_bounds__(256) k_scatter(const int* __restrict__ ei,
                                                 const int* __restrict__ flag,
                                                 const int* __restrict__ goff,
                                                 unsigned* __restrict__ tmp) {
    __shared__ int lcur[NBINS];
    int t = threadIdx.x, blk = blockIdx.x;
    for (int i = t; i < NBINS; i += 256) lcur[i] = 0;
    __syncthreads();
    int is64 = flag[0];
    int e0 = blk * EPB;
    for (int e = e0 + t; e < e0 + EPB; e += 256) {
        int s, d;
        if (is64) {
            s = ((const int2*)ei)[e].x;
            d = ((const int2*)ei)[NE + e].x;
        } else {
            s = ei[e];
            d = ei[NE + e];
        }
        int b = d >> 7;
        int lr = atomicAdd(&lcur[b], 1);
        int pos = goff[b * NBLK + blk] + lr;
        tmp[pos] = (unsigned)s | ((unsigned)(d & 127) << 17);
    }
}

__global__ void __launch_bounds__(256) k_deg(const unsigned* __restrict__ tmp,
                                             const int* __restrict__ goff,
                                             int* __restrict__ rs,
                                             int* __restrict__ deg32,
                                             float* __restrict__ dinv) {
    __shared__ int hist[128];
    int b = blockIdx.x, t = threadIdx.x;
    if (t < 128) hist[t] = 0;
    __syncthreads();
    int bs = goff[b * NBLK];
    int be = (b == NBINS - 1) ? NE : goff[(b + 1) * NBLK];
    for (int e = bs + t; e < be; e += 256)
        atomicAdd(&hist[tmp[e] >> 17], 1);
    __syncthreads();
    if (t < 128) {
        int node = b * 128 + t;
        if (node < NN) {
            int c = hist[t];
            int loff = 0;
            for (int i = 0; i < t; ++i) loff += hist[i];
            rs[node] = bs + loff;
            deg32[node] = c;
            dinv[node] = rsqrtf((float)c + 1.0f);
        }
    }
    if (b == 0 && t == 0) rs[NN] = NE;
}

// csr entry: (src*16) | (deg<<21) — src*16 is the uint2-row base (128 B rows).
__global__ void __launch_bounds__(256) k_csr(const unsigned* __restrict__ tmp,
                                             const int* __restrict__ goff,
                                             const int* __restrict__ rs,
                                             const int* __restrict__ deg32,
                                             unsigned* __restrict__ csr) {
    __shared__ int cur[128];
    __shared__ int base_sh[128];
    int b = blockIdx.x, t = threadIdx.x;
    if (t < 128) {
        cur[t] = 0;
        int node = b * 128 + t;
        base_sh[t] = (node < NN) ? rs[node] : 0;
    }
    __syncthreads();
    int bs = goff[b * NBLK];
    int be = (b == NBINS - 1) ? NE : goff[(b + 1) * NBLK];
    for (int e = bs + t; e < be; e += 256) {
        unsigned v = tmp[e];
        int dl = v >> 17;
        unsigned s = v & 0x1FFFFu;
        int lr = atomicAdd(&cur[dl], 1);
        unsigned deg = (unsigned)min(deg32[s], 2047);
        csr[base_sh[dl] + lr] = (s << 4) | (deg << 21);
    }
}

// ---------------- fp32 GEMM -> bf16 H: H[N,64] = X[N,64] @ W[64,64] ----------
// lane = row; fp32 accumulate; RNE-pack ALL 64 features -> 32 words (128 B/row).

__global__ void __launch_bounds__(256) k_gemm(const float* __restrict__ X,
                                              const float* __restrict__ W,
                                              unsigned* __restrict__ Hb) {
    int wid = (blockIdx.x * blockDim.x + threadIdx.x) >> 6;
    int nw = (gridDim.x * blockDim.x) >> 6;
    int lane = threadIdx.x & 63;
    const int ntiles = (NN + 63) >> 6;          // 1563 (last tile ragged)
    for (int t = wid; t < ntiles; t += nw) {
        int row = t * 64 + lane;
        int r = row < NN ? row : NN - 1;        // clamped lanes write duplicate data
        const float4* xp = (const float4*)(X + (size_t)r * 64);
        float acc[64];
#pragma unroll
        for (int c = 0; c < 64; ++c) acc[c] = 0.f;
#pragma unroll 4
        for (int k4 = 0; k4 < 16; ++k4) {
            float4 xv = xp[k4];
#pragma unroll
            for (int kj = 0; kj < 4; ++kj) {
                float xk = (kj == 0) ? xv.x : (kj == 1) ? xv.y : (kj == 2) ? xv.z : xv.w;
                const float4* wr = (const float4*)(W + (k4 * 4 + kj) * 64);
#pragma unroll
                for (int c4 = 0; c4 < 16; ++c4) {
                    float4 wv = wr[c4];
                    acc[c4 * 4 + 0] += xk * wv.x;
                    acc[c4 * 4 + 1] += xk * wv.y;
                    acc[c4 * 4 + 2] += xk * wv.z;
                    acc[c4 * 4 + 3] += xk * wv.w;
                }
            }
        }
        uint4* op = (uint4*)(Hb + (size_t)r * 32);   // 32 words = 64 bf16 = 128 B
#pragma unroll
        for (int q = 0; q < 8; ++q) {
            uint4 o;
            o.x = pack_bf16(acc[q * 8 + 0], acc[q * 8 + 1]);
            o.y = pack_bf16(acc[q * 8 + 2], acc[q * 8 + 3]);
            o.z = pack_bf16(acc[q * 8 + 4], acc[q * 8 + 5]);
            o.w = pack_bf16(acc[q * 8 + 6], acc[q * 8 + 7]);
            op[q] = o;
        }
    }
}

// ---------------- aggregation: one wave per node, 16 lanes x uint2(4xbf16),
// 4 lane-groups x 4-deep unroll => 16 x 128B row-gathers in flight ------------

__global__ void __launch_bounds__(256) k_agg(const uint2* __restrict__ hb,
                                             const int* __restrict__ rs,
                                             const unsigned* __restrict__ csr,
                                             const float* __restrict__ dinv,
                                             const float* __restrict__ bias,
                                             float4* __restrict__ out4) {
    int wid = (blockIdx.x * blockDim.x + threadIdx.x) >> 6;
    int lane = threadIdx.x & 63;
    int node = __builtin_amdgcn_readfirstlane(wid);
    if (node >= NN) return;
    int g = lane >> 4;        // edge-slot group 0..3
    int fl = lane & 15;       // feature quad 0..15
    float dn = dinv[node];
    int e0 = rs[node], e1 = rs[node + 1];
    uint2 sv = hb[node * 16 + fl];             // self row (bf16 x4)
    float ax = 0.f, ay = 0.f, az = 0.f, aw = 0.f;
    int e = e0 + g;
    for (; e + 12 < e1; e += 16) {             // 4 edges per group in flight
        unsigned p0 = csr[e];
        unsigned p1 = csr[e + 4];
        unsigned p2 = csr[e + 8];
        unsigned p3 = csr[e + 12];
        uint2 r0 = hb[(p0 & 0x1FFFFFu) + fl];
        uint2 r1 = hb[(p1 & 0x1FFFFFu) + fl];
        uint2 r2 = hb[(p2 & 0x1FFFFFu) + fl];
        uint2 r3 = hb[(p3 & 0x1FFFFFu) + fl];
        float w0 = rsqrtf((float)(p0 >> 21) + 1.0f);
        float w1 = rsqrtf((float)(p1 >> 21) + 1.0f);
        float w2 = rsqrtf((float)(p2 >> 21) + 1.0f);
        float w3 = rsqrtf((float)(p3 >> 21) + 1.0f);
        ax += BF_LO(r0.x) * w0; ay += BF_HI(r0.x) * w0;
        az += BF_LO(r0.y) * w0; aw += BF_HI(r0.y) * w0;
        ax += BF_LO(r1.x) * w1; ay += BF_HI(r1.x) * w1;
        az += BF_LO(r1.y) * w1; aw += BF_HI(r1.y) * w1;
        ax += BF_LO(r2.x) * w2; ay += BF_HI(r2.x) * w2;
        az += BF_LO(r2.y) * w2; aw += BF_HI(r2.y) * w2;
        ax += BF_LO(r3.x) * w3; ay += BF_HI(r3.x) * w3;
        az += BF_LO(r3.y) * w3; aw += BF_HI(r3.y) * w3;
    }
    for (; e < e1; e += 4) {
        unsigned p0 = csr[e];
        uint2 r0 = hb[(p0 & 0x1FFFFFu) + fl];
        float w0 = rsqrtf((float)(p0 >> 21) + 1.0f);
        ax += BF_LO(r0.x) * w0; ay += BF_HI(r0.x) * w0;
        az += BF_LO(r0.y) * w0; aw += BF_HI(r0.y) * w0;
    }
    ax += __shfl_xor(ax, 16); ay += __shfl_xor(ay, 16);
    az += __shfl_xor(az, 16); aw += __shfl_xor(aw, 16);
    ax += __shfl_xor(ax, 32); ay += __shfl_xor(ay, 32);
    az += __shfl_xor(az, 32); aw += __shfl_xor(aw, 32);
    if (lane < 16) {
        const float4 b4 = *(const float4*)&bias[fl * 4];
        float4 res;
        res.x = fmaxf((ax + BF_LO(sv.x) * dn) * dn + b4.x, 0.f);
        res.y = fmaxf((ay + BF_HI(sv.x) * dn) * dn + b4.y, 0.f);
        res.z = fmaxf((az + BF_LO(sv.y) * dn) * dn + b4.z, 0.f);
        res.w = fmaxf((aw + BF_HI(sv.y) * dn) * dn + b4.w, 0.f);
        out4[node * 16 + fl] = res;
    }
}

// ---------------- launch ----------------

extern "C" void kernel_launch(void* const* d_in, const int* in_sizes, int n_in,
                              void* d_out, int out_size, void* d_ws, size_t ws_size,
                              hipStream_t stream) {
    const float* x  = (const float*)d_in[0];            // [NN,64] fp32
    const int* ei   = (const int*)d_in[1];              // [2,NE] int32/int64 (detected)
    const float* W1 = (const float*)d_in[2];
    const float* b1 = (const float*)d_in[3];
    const float* W2 = (const float*)d_in[4];
    const float* b2 = (const float*)d_in[5];

    char* ws = (char*)d_ws;
    size_t off = 0;
    auto alloc = [&](size_t bytes) -> char* {
        char* p = ws + off;
        off = (off + bytes + 511) & ~(size_t)511;
        return p;
    };
    int*      flag  = (int*)alloc(64);
    int*      gcount= (int*)alloc((size_t)NCELL * 4);    // 800 KB
    int*      goff  = (int*)alloc((size_t)NCELL * 4);    // 800 KB
    int*      bsum  = (int*)alloc((size_t)NSB * 4);
    int*      boff  = (int*)alloc((size_t)NSB * 4);
    unsigned* tmp   = (unsigned*)alloc((size_t)NE * 4);  // 6.4 MB
    unsigned* csr   = (unsigned*)alloc((size_t)NE * 4);  // 6.4 MB
    int*      rs    = (int*)alloc((size_t)(NN + 1) * 4);
    int*      deg32 = (int*)alloc((size_t)NN * 4);
    float*    dinv  = (float*)alloc((size_t)NN * 4);
    unsigned* hbuf  = (unsigned*)alloc((size_t)NN * 32 * 4);  // 12.8 MB bf16 h (128 B rows)
    float*    hmid  = (float*)d_out;                     // layer-1 fp32 act (reuse d_out)

    k_detect<<<1, 64, 0, stream>>>(ei, flag);
    k_hist<<<NBLK, 256, 0, stream>>>(ei, flag, gcount);
    k_pscan1<<<NSB, 256, 0, stream>>>(gcount, bsum);
    k_pscan2<<<1, 256, 0, stream>>>(bsum, boff);
    k_pscan3<<<NSB, 256, 0, stream>>>(gcount, boff, goff);
    k_scatter<<<NBLK, 256, 0, stream>>>(ei, flag, goff, tmp);
    k_deg<<<NBINS, 256, 0, stream>>>(tmp, goff, rs, deg32, dinv);
    k_csr<<<NBINS, 256, 0, stream>>>(tmp, goff, rs, deg32, csr);

    // layer 1: hbuf(bf16) = x @ W1 ; hmid(=d_out, fp32) = relu(agg(hbuf) + b1)
    k_gemm<<<391, 256, 0, stream>>>(x, W1, hbuf);
    k_agg<<<(NN * 64) / 256, 256, 0, stream>>>((const uint2*)hbuf, rs, csr, dinv, b1,
                                               (float4*)hmid);
    // layer 2: hbuf(bf16) = hmid @ W2 ; d_out = relu(agg(hbuf) + b2)
    k_gemm<<<391, 256, 0, stream>>>(hmid, W2, hbuf);
    k_agg<<<(NN * 64) / 256, 256, 0, stream>>>((const uint2*)hbuf, rs, csr, dinv, b2,
                                               (float4*)d_out);
}